// Round 7
// baseline (2159.528 us; speedup 1.0000x reference)
//
#include <hip/hip_runtime.h>
#include <cstdint>

#define NN 100000
#define NE 250000
#define MP 100096   // 3128 * 32
#define SCAN_B 256
#define NBLK ((NN + SCAN_B - 1) / SCAN_B)   // 391
#define NSLOT 32

using bf16x8 = __attribute__((ext_vector_type(8))) __bf16;
using f32x4v = __attribute__((ext_vector_type(4))) float;

__device__ __forceinline__ unsigned short f2bf(float f) {
  union { float f; uint32_t u; } v; v.f = f;
  uint32_t r = v.u + 0x7FFFu + ((v.u >> 16) & 1u);
  return (unsigned short)(r >> 16);
}
__device__ __forceinline__ float bf2f(unsigned short u) {
  union { uint32_t u; float f; } v; v.u = ((uint32_t)u) << 16;
  return v.f;
}

__device__ __forceinline__ void ld_lds16(const void* g, void* l) {
  __builtin_amdgcn_global_load_lds(
      (const __attribute__((address_space(1))) void*)g,
      (__attribute__((address_space(3))) void*)l, 16, 0, 0);
}

// ---------------- prep: transpose+pad weights to bf16, combos, biases, zero BN sums
__global__ void prep_kernel(const float* __restrict__ W1, const float* __restrict__ W2,
                            const float* __restrict__ ee1, const float* __restrict__ ee2,
                            const float* __restrict__ b1, const float* __restrict__ b2, int l,
                            unsigned short* __restrict__ wt1, unsigned short* __restrict__ wt2,
                            float* __restrict__ combo, float* __restrict__ selfv,
                            float* __restrict__ b1p, float* __restrict__ b2p,
                            float* __restrict__ bnsum, float* __restrict__ bnsum2) {
  int i = blockIdx.x * 256 + threadIdx.x;
  if (i < 640 * 320) {                       // wt1[n][k] = W1[l][k][n], pad to 640x320
    int n = i / 320, k = i % 320;
    float v = (n < 600 && k < 300) ? W1[(size_t)l * 180000 + k * 600 + n] : 0.f;
    wt1[i] = f2bf(v); return;
  }
  i -= 640 * 320;
  if (i < 384 * 640) {                       // wt2[n][k] = W2[l][k][n], pad to 384x640
    int n = i / 640, k = i % 640;
    float v = (n < 300 && k < 600) ? W2[(size_t)l * 180000 + k * 300 + n] : 0.f;
    wt2[i] = f2bf(v); return;
  }
  i -= 384 * 640;
  if (i < 3600) {                            // 12 edge-embedding combos [12][300]
    int idx = i / 300, d = i % 300;
    int a = idx / 3, b = idx % 3;
    combo[i] = ee1[l * 1800 + a * 300 + d] + ee2[l * 900 + b * 300 + d]; return;
  }
  i -= 3600;
  if (i < 300) { selfv[i] = ee1[l * 1800 + 4 * 300 + i] + ee2[l * 900 + i]; return; }
  i -= 300;
  if (i < 640) { b1p[i] = (i < 600) ? b1[l * 600 + i] : 0.f; return; }
  i -= 640;
  if (i < 384) { b2p[i] = (i < 300) ? b2[l * 300 + i] : 0.f; return; }
  i -= 384;
  if (i < NSLOT * 384) { bnsum[i] = 0.f; return; }
  i -= NSLOT * 384;
  if (i < NSLOT * 384) { bnsum2[i] = 0.f; return; }
}
#define PREP_TOT (640*320 + 384*640 + 3600 + 300 + 640 + 384 + 2*NSLOT*384)

// ---------------- CSR build: degree histogram
__global__ void deg_kernel(const int* __restrict__ ei, int* __restrict__ deg) {
  int e = blockIdx.x * 256 + threadIdx.x;
  if (e >= NE) return;
  atomicAdd(&deg[ei[NE + e]], 1);
}

// ---------------- exclusive scan (3 kernels)
__global__ void scan1_kernel(const int* __restrict__ deg, int* __restrict__ off,
                             int* __restrict__ bsum) {
  __shared__ int tmp[SCAN_B];
  int b = blockIdx.x, t = threadIdx.x;
  int i = b * SCAN_B + t;
  int v = (i < NN) ? deg[i] : 0;
  tmp[t] = v;
  __syncthreads();
  for (int s = 1; s < SCAN_B; s <<= 1) {
    int a = (t >= s) ? tmp[t - s] : 0;
    __syncthreads();
    tmp[t] += a;
    __syncthreads();
  }
  if (i < NN) off[i] = tmp[t] - v;           // exclusive
  if (t == SCAN_B - 1) bsum[b] = tmp[t];
}
__global__ void scan2_kernel(int* __restrict__ bsum) {
  if (threadIdx.x == 0) {
    int acc = 0;
    for (int b = 0; b < NBLK; ++b) { int v = bsum[b]; bsum[b] = acc; acc += v; }
  }
}
__global__ void scan3_kernel(const int* __restrict__ bsum, int* __restrict__ off,
                             int* __restrict__ cursor) {
  int i = blockIdx.x * SCAN_B + threadIdx.x;
  if (i >= NN) return;
  int o = off[i] + bsum[blockIdx.x];
  off[i] = o;
  cursor[i] = o;
}

// ---------------- CSR fill: list[p] = src*16 + combo_idx
__global__ void fill_kernel(const int* __restrict__ ei, const int* __restrict__ ea,
                            int* __restrict__ cursor, int* __restrict__ list) {
  int e = blockIdx.x * 256 + threadIdx.x;
  if (e >= NE) return;
  int s = ei[e], d = ei[NE + e];
  int c = ea[2 * e] * 3 + ea[2 * e + 1];
  int p = atomicAdd(&cursor[d], 1);
  list[p] = s * 16 + c;
}

// ---------------- gather (fused BN-apply + ReLU + aggregate + (1+eps)* + bf16 cast)
// MODE 0: source row = x_emb1[x0[s]] + x_emb2[x1[s]]          (layer 0, no BN)
// MODE 1: source row = relu(bf16z[s]*bnA + bnB)               (layers 1..4)
template <int MODE>
__global__ void gather_kernel(const unsigned short* __restrict__ zsrc,
                              const int* __restrict__ x, const float* __restrict__ e1,
                              const float* __restrict__ e2,
                              const float* __restrict__ bnA, const float* __restrict__ bnB,
                              const int* __restrict__ off, const int* __restrict__ deg,
                              const int* __restrict__ list,
                              const float* __restrict__ combo, const float* __restrict__ selfv,
                              const float* __restrict__ eps, int l,
                              unsigned short* __restrict__ abf) {
  int i = blockIdx.x * 256 + threadIdx.x;
  if (i >= NN * 75) return;
  int r = i / 75, q = i % 75;
  float4 a4, b4;
  if (MODE == 1) { a4 = ((const float4*)bnA)[q]; b4 = ((const float4*)bnB)[q]; }

  const ushort4* z4 = (const ushort4*)zsrc;
  const float4* c4 = (const float4*)combo;

  auto loadrow = [&](int s) -> float4 {
    float4 hv;
    if (MODE == 0) {
      float4 u = ((const float4*)(e1 + (size_t)x[2 * s] * 300))[q];
      float4 v = ((const float4*)(e2 + (size_t)x[2 * s + 1] * 300))[q];
      hv.x = u.x + v.x; hv.y = u.y + v.y; hv.z = u.z + v.z; hv.w = u.w + v.w;
    } else {
      ushort4 zv = z4[(size_t)s * 96 + q];
      hv.x = fmaxf(bf2f(zv.x) * a4.x + b4.x, 0.f);
      hv.y = fmaxf(bf2f(zv.y) * a4.y + b4.y, 0.f);
      hv.z = fmaxf(bf2f(zv.z) * a4.z + b4.z, 0.f);
      hv.w = fmaxf(bf2f(zv.w) * a4.w + b4.w, 0.f);
    }
    return hv;
  };

  float4 acc = loadrow(r);
  float4 sv = ((const float4*)selfv)[q];
  acc.x += sv.x; acc.y += sv.y; acc.z += sv.z; acc.w += sv.w;

  int p0 = off[r], dn = deg[r];
  for (int p = 0; p < dn; ++p) {
    int pk = list[p0 + p];
    int s = pk >> 4, c = pk & 15;
    float4 hv = loadrow(s);
    float4 cv = c4[c * 75 + q];
    acc.x += hv.x + cv.x; acc.y += hv.y + cv.y;
    acc.z += hv.z + cv.z; acc.w += hv.w + cv.w;
  }
  float sc = 1.f + eps[l];
  ushort4 o;
  o.x = f2bf(acc.x * sc); o.y = f2bf(acc.y * sc);
  o.z = f2bf(acc.z * sc); o.w = f2bf(acc.w * sc);
  *(ushort4*)(abf + (size_t)r * 320 + q * 4) = o;
}

// ---------------- fused MLP: z = (relu(A@W1^T+b1))@W2^T + b2, BN stats fused.
// Per block: 32-row strip. A strip staged once to LDS (chunk-XOR swizzle).
// Phase 1 (operand-swapped MFMA -> C col = m): z1[32][640] written to LDS in
// phase-2 A-fragment layout (row m, k2-contiguous, XOR-swizzled). Phase 2 reads
// z1 via ds_read_b128, W1/W2 fragments come per-lane from global (L2-resident).
// No barriers inside k-loops; 2 __syncthreads total.
__global__ __launch_bounds__(256, 2) void fused_mlp_kernel(
    const unsigned short* __restrict__ abf, const unsigned short* __restrict__ wt1,
    const unsigned short* __restrict__ wt2, const float* __restrict__ b1p,
    const float* __restrict__ b2p, unsigned short* __restrict__ zf,
    float* __restrict__ bnsum, float* __restrict__ bnsum2) {
  __shared__ unsigned short AsL[32 * 320];   // 20 KB: A strip, chunk-swizzled
  __shared__ unsigned short z1L[32 * 640];   // 40 KB: z1 strip, row-XOR-swizzled
  const int tid = threadIdx.x;
  const int lane = tid & 63;
  const int w = tid >> 6;          // 4 waves
  const int l15 = lane & 15, l4 = lane >> 4;
  const int bm = blockIdx.x * 32;

  // ---- stage A strip [32][320]: LDS slot (m,c) holds global chunk c^(m&7)
#pragma unroll
  for (int it = 0; it < 5; ++it) {
    int s = it * 256 + tid;              // 0..1279 (16B chunks)
    int m = s / 40, c = s % 40;
    int cg = c ^ (m & 7);
    ld_lds16(abf + (size_t)(bm + m) * 320 + cg * 8, (char*)AsL + s * 16);
  }
  __syncthreads();                        // drains vmcnt: A strip resident

  // ---- phase 1: wave owns n1-slice [w*160, w*160+160)
  f32x4v acc1[10][2] = {};
#pragma unroll
  for (int kc = 0; kc < 10; ++kc) {
    bf16x8 fA[2], fW[10];
#pragma unroll
    for (int mf = 0; mf < 2; ++mf) {
      int m = mf * 16 + l15;
      int cR = kc * 4 + l4;              // 16B chunk index within row
      fA[mf] = *reinterpret_cast<const bf16x8*>(
          (const char*)AsL + m * 640 + ((cR ^ (m & 7)) << 4));
    }
#pragma unroll
    for (int nf = 0; nf < 10; ++nf) {
      int n1 = w * 160 + nf * 16 + l15;
      fW[nf] = *reinterpret_cast<const bf16x8*>(wt1 + (size_t)n1 * 320 + kc * 32 + l4 * 8);
    }
#pragma unroll
    for (int nf = 0; nf < 10; ++nf)
#pragma unroll
      for (int mf = 0; mf < 2; ++mf)
        acc1[nf][mf] = __builtin_amdgcn_mfma_f32_16x16x32_bf16(fW[nf], fA[mf], acc1[nf][mf], 0, 0, 0);
  }

  // epilogue-1: bias+relu, pack 4 bf16 (4 consecutive n1, fixed m) -> LDS b64
#pragma unroll
  for (int nf = 0; nf < 10; ++nf) {
    int Nb = w * 160 + nf * 16 + (l4 << 2);      // n1 base of this lane's 4 vals
    float4 bb = *(const float4*)(b1p + Nb);
#pragma unroll
    for (int mf = 0; mf < 2; ++mf) {
      int m = mf * 16 + l15;
      float v0 = fmaxf(acc1[nf][mf][0] + bb.x, 0.f);
      float v1 = fmaxf(acc1[nf][mf][1] + bb.y, 0.f);
      float v2 = fmaxf(acc1[nf][mf][2] + bb.z, 0.f);
      float v3 = fmaxf(acc1[nf][mf][3] + bb.w, 0.f);
      uint2 p;
      p.x = (uint32_t)f2bf(v0) | ((uint32_t)f2bf(v1) << 16);
      p.y = (uint32_t)f2bf(v2) | ((uint32_t)f2bf(v3) << 16);
      *(uint2*)((char*)z1L + m * 1280 + (((Nb << 1)) ^ ((m & 7) << 4))) = p;
    }
  }
  __syncthreads();                        // z1 complete (drains lgkm)

  // ---- phase 2: wave owns n2-slice [w*96, w*96+96)
  f32x4v acc2[2][6] = {};
#pragma unroll
  for (int kc = 0; kc < 20; ++kc) {
    bf16x8 fz[2], fW2[6];
#pragma unroll
    for (int mf = 0; mf < 2; ++mf) {
      int m = mf * 16 + l15;
      fz[mf] = *reinterpret_cast<const bf16x8*>(
          (const char*)z1L + m * 1280 + ((kc * 64 + (l4 << 4)) ^ ((m & 7) << 4)));
    }
#pragma unroll
    for (int nf = 0; nf < 6; ++nf) {
      int n2 = w * 96 + nf * 16 + l15;
      fW2[nf] = *reinterpret_cast<const bf16x8*>(wt2 + (size_t)n2 * 640 + kc * 32 + l4 * 8);
    }
#pragma unroll
    for (int mf = 0; mf < 2; ++mf)
#pragma unroll
      for (int nf = 0; nf < 6; ++nf)
        acc2[mf][nf] = __builtin_amdgcn_mfma_f32_16x16x32_bf16(fz[mf], fW2[nf], acc2[mf][nf], 0, 0, 0);
  }

  // epilogue-2: bias, bf16 store, slot-split BN stats
  const int slot = blockIdx.x & (NSLOT - 1);
#pragma unroll
  for (int nf = 0; nf < 6; ++nf) {
    int col = w * 96 + nf * 16 + l15;
    float bv = b2p[col];
    float s = 0.f, s2 = 0.f;
#pragma unroll
    for (int mf = 0; mf < 2; ++mf) {
      int row0 = bm + mf * 16 + (l4 << 2);
#pragma unroll
      for (int r = 0; r < 4; ++r) {
        float v = acc2[mf][nf][r] + bv;
        zf[(size_t)(row0 + r) * 384 + col] = f2bf(v);
        if ((row0 + r) < NN) { s += v; s2 += v * v; }
      }
    }
    s  += __shfl_xor(s, 16);  s  += __shfl_xor(s, 32);
    s2 += __shfl_xor(s2, 16); s2 += __shfl_xor(s2, 32);
    if (l4 == 0) {
      atomicAdd(&bnsum[slot * 384 + col], s);
      atomicAdd(&bnsum2[slot * 384 + col], s2);
    }
  }
}

__global__ void bnfinal_kernel(const float* __restrict__ bnsum, const float* __restrict__ bnsum2,
                               const float* __restrict__ gamma, const float* __restrict__ beta,
                               int l, float* __restrict__ Aout, float* __restrict__ Bout) {
  int c = threadIdx.x;
  if (c >= 300) return;
  float s = 0.f, s2 = 0.f;
  for (int k = 0; k < NSLOT; ++k) { s += bnsum[k * 384 + c]; s2 += bnsum2[k * 384 + c]; }
  float mean = s * (1.f / NN);
  float var = s2 * (1.f / NN) - mean * mean;
  var = fmaxf(var, 0.f);
  float inv = rsqrtf(var + 1e-5f);
  float a = gamma[l * 300 + c] * inv;
  Aout[c] = a;
  Bout[c] = beta[l * 300 + c] - mean * a;
}

// ---------------- final BN apply (layer 4, no ReLU): d_out[N][300] = bf2f(z)*A + B
__global__ void bnapply_kernel(const unsigned short* __restrict__ z, const float* __restrict__ Ain,
                               const float* __restrict__ Bin, float* __restrict__ out) {
  int i = blockIdx.x * 256 + threadIdx.x;
  if (i >= NN * 75) return;
  int r = i / 75, q = i % 75;
  ushort4 zv = ((const ushort4*)z)[(size_t)r * 96 + q];
  float4 a = ((const float4*)Ain)[q];
  float4 b = ((const float4*)Bin)[q];
  float4 o;
  o.x = bf2f(zv.x) * a.x + b.x; o.y = bf2f(zv.y) * a.y + b.y;
  o.z = bf2f(zv.z) * a.z + b.z; o.w = bf2f(zv.w) * a.w + b.w;
  ((float4*)out)[i] = o;
}

// ---------------- workspace layout (bytes, all 256-aligned)
constexpr size_t OFF_Z    = 0;                               // z bf16 [MP][384]
constexpr size_t OFF_AB   = OFF_Z  + (size_t)MP * 384 * 2;   // abf16 [MP][320]
constexpr size_t OFF_WT1  = OFF_AB + (size_t)MP * 320 * 2;   // wt1 bf16 [640][320]
constexpr size_t OFF_WT2  = OFF_WT1 + 640 * 320 * 2;
constexpr size_t OFF_CMB  = OFF_WT2 + 384 * 640 * 2;
constexpr size_t OFF_SLF  = OFF_CMB + 14592;
constexpr size_t OFF_B1   = OFF_SLF + 1280;
constexpr size_t OFF_B2   = OFF_B1 + 2560;
constexpr size_t OFF_S1   = OFF_B2 + 1536;                   // bnsum  f32 [32][384]
constexpr size_t OFF_S2   = OFF_S1 + NSLOT * 384 * 4;        // bnsum2 f32 [32][384]
constexpr size_t OFF_BA   = OFF_S2 + NSLOT * 384 * 4;
constexpr size_t OFF_BB   = OFF_BA + 1536;
constexpr size_t OFF_DEG  = OFF_BB + 1536;              // int[NN]
constexpr size_t OFF_OFFS = OFF_DEG + 400384;           // int[NN]
constexpr size_t OFF_CUR  = OFF_OFFS + 400384;          // int[NN]
constexpr size_t OFF_BS   = OFF_CUR + 400384;           // int[NBLK]
constexpr size_t OFF_LIST = OFF_BS + 2048;              // int[NE]

extern "C" void kernel_launch(void* const* d_in, const int* in_sizes, int n_in,
                              void* d_out, int out_size, void* d_ws, size_t ws_size,
                              hipStream_t stream) {
  const int*   x     = (const int*)d_in[0];
  const int*   ei    = (const int*)d_in[1];
  const int*   ea    = (const int*)d_in[2];
  const float* xe1   = (const float*)d_in[3];
  const float* xe2   = (const float*)d_in[4];
  const float* ee1   = (const float*)d_in[5];
  const float* ee2   = (const float*)d_in[6];
  const float* W1    = (const float*)d_in[7];
  const float* b1    = (const float*)d_in[8];
  const float* W2    = (const float*)d_in[9];
  const float* b2    = (const float*)d_in[10];
  const float* eps   = (const float*)d_in[11];
  const float* gamma = (const float*)d_in[12];
  const float* beta  = (const float*)d_in[13];

  char* ws = (char*)d_ws;
  unsigned short* zf    = (unsigned short*)(ws + OFF_Z);
  unsigned short* abf   = (unsigned short*)(ws + OFF_AB);
  unsigned short* wt1   = (unsigned short*)(ws + OFF_WT1);
  unsigned short* wt2   = (unsigned short*)(ws + OFF_WT2);
  float*          combo = (float*)(ws + OFF_CMB);
  float*          selfv = (float*)(ws + OFF_SLF);
  float*          b1p   = (float*)(ws + OFF_B1);
  float*          b2p   = (float*)(ws + OFF_B2);
  float*          bns   = (float*)(ws + OFF_S1);
  float*          bns2  = (float*)(ws + OFF_S2);
  float*          bnA   = (float*)(ws + OFF_BA);
  float*          bnB   = (float*)(ws + OFF_BB);
  int*            deg   = (int*)(ws + OFF_DEG);
  int*            offs  = (int*)(ws + OFF_OFFS);
  int*            cur   = (int*)(ws + OFF_CUR);
  int*            bsum  = (int*)(ws + OFF_BS);
  int*            list  = (int*)(ws + OFF_LIST);

  const int g_ew   = (NN * 75 + 255) / 256;
  const int g_e    = (NE + 255) / 256;
  const int g_prep = (PREP_TOT + 255) / 256;

  // one-time per launch: zero abf (pad rows/cols stay 0 across layers), deg
  hipMemsetAsync(abf, 0, (size_t)MP * 320 * 2, stream);
  hipMemsetAsync(deg, 0, NN * 4, stream);

  // CSR build (graph static across layers)
  deg_kernel<<<g_e, 256, 0, stream>>>(ei, deg);
  scan1_kernel<<<NBLK, SCAN_B, 0, stream>>>(deg, offs, bsum);
  scan2_kernel<<<1, 64, 0, stream>>>(bsum);
  scan3_kernel<<<NBLK, SCAN_B, 0, stream>>>(bsum, offs, cur);
  fill_kernel<<<g_e, 256, 0, stream>>>(ei, ea, cur, list);

  for (int l = 0; l < 5; ++l) {
    prep_kernel<<<g_prep, 256, 0, stream>>>(W1, W2, ee1, ee2, b1, b2, l,
                                            wt1, wt2, combo, selfv, b1p, b2p, bns, bns2);
    if (l == 0)
      gather_kernel<0><<<g_ew, 256, 0, stream>>>(zf, x, xe1, xe2, bnA, bnB,
                                                 offs, deg, list, combo, selfv, eps, l, abf);
    else
      gather_kernel<1><<<g_ew, 256, 0, stream>>>(zf, x, xe1, xe2, bnA, bnB,
                                                 offs, deg, list, combo, selfv, eps, l, abf);
    fused_mlp_kernel<<<MP / 32, 256, 0, stream>>>(abf, wt1, wt2, b1p, b2p, zf, bns, bns2);
    bnfinal_kernel<<<1, 384, 0, stream>>>(bns, bns2, gamma, beta, l, bnA, bnB);
  }
  bnapply_kernel<<<g_ew, 256, 0, stream>>>(zf, bnA, bnB, (float*)d_out);
}

// Round 8
// 1193.109 us; speedup vs baseline: 1.8100x; 1.8100x over previous
//
#include <hip/hip_runtime.h>
#include <cstdint>

#define NN 100000
#define NE 250000
#define MP 100096   // 391 * 256
#define MSTRIP 391
#define SCAN_B 256
#define NBLK ((NN + SCAN_B - 1) / SCAN_B)   // 391
#define NSLOT 32

using bf16x8 = __attribute__((ext_vector_type(8))) __bf16;
using f32x4v = __attribute__((ext_vector_type(4))) float;

__device__ __forceinline__ unsigned short f2bf(float f) {
  union { float f; uint32_t u; } v; v.f = f;
  uint32_t r = v.u + 0x7FFFu + ((v.u >> 16) & 1u);
  return (unsigned short)(r >> 16);
}
__device__ __forceinline__ float bf2f(unsigned short u) {
  union { uint32_t u; float f; } v; v.u = ((uint32_t)u) << 16;
  return v.f;
}

__device__ __forceinline__ void ld_lds16(const void* g, void* l) {
  __builtin_amdgcn_global_load_lds(
      (const __attribute__((address_space(1))) void*)g,
      (__attribute__((address_space(3))) void*)l, 16, 0, 0);
}

// ---------------- prep: transpose+pad weights to bf16, combos, biases, zero BN sums
__global__ void prep_kernel(const float* __restrict__ W1, const float* __restrict__ W2,
                            const float* __restrict__ ee1, const float* __restrict__ ee2,
                            const float* __restrict__ b1, const float* __restrict__ b2, int l,
                            unsigned short* __restrict__ wt1, unsigned short* __restrict__ wt2,
                            float* __restrict__ combo, float* __restrict__ selfv,
                            float* __restrict__ b1p, float* __restrict__ b2p,
                            float* __restrict__ bnsum, float* __restrict__ bnsum2) {
  int i = blockIdx.x * 256 + threadIdx.x;
  if (i < 640 * 320) {                       // wt1[n][k] = W1[l][k][n], pad to 640x320
    int n = i / 320, k = i % 320;
    float v = (n < 600 && k < 300) ? W1[(size_t)l * 180000 + k * 600 + n] : 0.f;
    wt1[i] = f2bf(v); return;
  }
  i -= 640 * 320;
  if (i < 384 * 640) {                       // wt2[n][k] = W2[l][k][n], pad to 384x640
    int n = i / 640, k = i % 640;
    float v = (n < 300 && k < 600) ? W2[(size_t)l * 180000 + k * 300 + n] : 0.f;
    wt2[i] = f2bf(v); return;
  }
  i -= 384 * 640;
  if (i < 3600) {                            // 12 edge-embedding combos [12][300]
    int idx = i / 300, d = i % 300;
    int a = idx / 3, b = idx % 3;
    combo[i] = ee1[l * 1800 + a * 300 + d] + ee2[l * 900 + b * 300 + d]; return;
  }
  i -= 3600;
  if (i < 300) { selfv[i] = ee1[l * 1800 + 4 * 300 + i] + ee2[l * 900 + i]; return; }
  i -= 300;
  if (i < 640) { b1p[i] = (i < 600) ? b1[l * 600 + i] : 0.f; return; }
  i -= 640;
  if (i < 384) { b2p[i] = (i < 300) ? b2[l * 300 + i] : 0.f; return; }
  i -= 384;
  if (i < NSLOT * 384) { bnsum[i] = 0.f; return; }
  i -= NSLOT * 384;
  if (i < NSLOT * 384) { bnsum2[i] = 0.f; return; }
}
#define PREP_TOT (640*320 + 384*640 + 3600 + 300 + 640 + 384 + 2*NSLOT*384)

// ---------------- CSR build: degree histogram
__global__ void deg_kernel(const int* __restrict__ ei, int* __restrict__ deg) {
  int e = blockIdx.x * 256 + threadIdx.x;
  if (e >= NE) return;
  atomicAdd(&deg[ei[NE + e]], 1);
}

// ---------------- exclusive scan (3 kernels)
__global__ void scan1_kernel(const int* __restrict__ deg, int* __restrict__ off,
                             int* __restrict__ bsum) {
  __shared__ int tmp[SCAN_B];
  int b = blockIdx.x, t = threadIdx.x;
  int i = b * SCAN_B + t;
  int v = (i < NN) ? deg[i] : 0;
  tmp[t] = v;
  __syncthreads();
  for (int s = 1; s < SCAN_B; s <<= 1) {
    int a = (t >= s) ? tmp[t - s] : 0;
    __syncthreads();
    tmp[t] += a;
    __syncthreads();
  }
  if (i < NN) off[i] = tmp[t] - v;           // exclusive
  if (t == SCAN_B - 1) bsum[b] = tmp[t];
}
__global__ void scan2_kernel(int* __restrict__ bsum) {
  if (threadIdx.x == 0) {
    int acc = 0;
    for (int b = 0; b < NBLK; ++b) { int v = bsum[b]; bsum[b] = acc; acc += v; }
  }
}
__global__ void scan3_kernel(const int* __restrict__ bsum, int* __restrict__ off,
                             int* __restrict__ cursor) {
  int i = blockIdx.x * SCAN_B + threadIdx.x;
  if (i >= NN) return;
  int o = off[i] + bsum[blockIdx.x];
  off[i] = o;
  cursor[i] = o;
}

// ---------------- CSR fill: list[p] = src*16 + combo_idx
__global__ void fill_kernel(const int* __restrict__ ei, const int* __restrict__ ea,
                            int* __restrict__ cursor, int* __restrict__ list) {
  int e = blockIdx.x * 256 + threadIdx.x;
  if (e >= NE) return;
  int s = ei[e], d = ei[NE + e];
  int c = ea[2 * e] * 3 + ea[2 * e + 1];
  int p = atomicAdd(&cursor[d], 1);
  list[p] = s * 16 + c;
}

// ---------------- gather (fused BN-apply + ReLU + aggregate + (1+eps)* + bf16 cast)
// MODE 0: source row = x_emb1[x0[s]] + x_emb2[x1[s]]          (layer 0, no BN)
// MODE 1: source row = relu(bf16z[s]*bnA + bnB)               (layers 1..4)
template <int MODE>
__global__ void gather_kernel(const unsigned short* __restrict__ zsrc,
                              const int* __restrict__ x, const float* __restrict__ e1,
                              const float* __restrict__ e2,
                              const float* __restrict__ bnA, const float* __restrict__ bnB,
                              const int* __restrict__ off, const int* __restrict__ deg,
                              const int* __restrict__ list,
                              const float* __restrict__ combo, const float* __restrict__ selfv,
                              const float* __restrict__ eps, int l,
                              unsigned short* __restrict__ abf) {
  int i = blockIdx.x * 256 + threadIdx.x;
  if (i >= NN * 75) return;
  int r = i / 75, q = i % 75;
  float4 a4, b4;
  if (MODE == 1) { a4 = ((const float4*)bnA)[q]; b4 = ((const float4*)bnB)[q]; }

  const ushort4* z4 = (const ushort4*)zsrc;
  const float4* c4 = (const float4*)combo;

  auto loadrow = [&](int s) -> float4 {
    float4 hv;
    if (MODE == 0) {
      float4 u = ((const float4*)(e1 + (size_t)x[2 * s] * 300))[q];
      float4 v = ((const float4*)(e2 + (size_t)x[2 * s + 1] * 300))[q];
      hv.x = u.x + v.x; hv.y = u.y + v.y; hv.z = u.z + v.z; hv.w = u.w + v.w;
    } else {
      ushort4 zv = z4[(size_t)s * 96 + q];
      hv.x = fmaxf(bf2f(zv.x) * a4.x + b4.x, 0.f);
      hv.y = fmaxf(bf2f(zv.y) * a4.y + b4.y, 0.f);
      hv.z = fmaxf(bf2f(zv.z) * a4.z + b4.z, 0.f);
      hv.w = fmaxf(bf2f(zv.w) * a4.w + b4.w, 0.f);
    }
    return hv;
  };

  float4 acc = loadrow(r);
  float4 sv = ((const float4*)selfv)[q];
  acc.x += sv.x; acc.y += sv.y; acc.z += sv.z; acc.w += sv.w;

  int p0 = off[r], dn = deg[r];
  for (int p = 0; p < dn; ++p) {
    int pk = list[p0 + p];
    int s = pk >> 4, c = pk & 15;
    float4 hv = loadrow(s);
    float4 cv = c4[c * 75 + q];
    acc.x += hv.x + cv.x; acc.y += hv.y + cv.y;
    acc.z += hv.z + cv.z; acc.w += hv.w + cv.w;
  }
  float sc = 1.f + eps[l];
  ushort4 o;
  o.x = f2bf(acc.x * sc); o.y = f2bf(acc.y * sc);
  o.z = f2bf(acc.z * sc); o.w = f2bf(acc.w * sc);
  *(ushort4*)(abf + (size_t)r * 320 + q * 4) = o;
}

// ---------------- bf16 MFMA GEMM: C[M][NS] = A[M][LDA] @ B^T (B is [n][k]) + bias
// 8-wave blocks, BM=256 x BN=128. Double-buffered LDS, counted-vmcnt prefetch
// (raw s_barrier, no drain-0 until tail). XCD remap: NT column-blocks of one
// row-strip are dispatch-adjacent on the same XCD (wid%8) -> A-strip L2-hot.
// STATS: per-column sum/sumsq of output (rows < NN), slot-split 32x.
template <int LDA, int LDB, int NS, int NT, bool RELU, bool OBF16, bool STATS>
__global__ __launch_bounds__(512, 4) void gemm_kernel(
    const unsigned short* __restrict__ A, const unsigned short* __restrict__ B,
    const float* __restrict__ bias, void* __restrict__ C, int K,
    float* __restrict__ bnsum, float* __restrict__ bnsum2) {
  __shared__ unsigned short As[2][256 * 32];   // 2 x 16 KB
  __shared__ unsigned short Bs[2][128 * 32];   // 2 x 8 KB
  const int tid = threadIdx.x;
  const int lane = tid & 63;
  const int w = tid >> 6;            // 8 waves: wr = w>>1 (M), wc = w&1 (N)
  const int wr = w >> 1, wc = w & 1;
  const int l15 = lane & 15, l4 = lane >> 4;

  const int wid = blockIdx.x + gridDim.x * blockIdx.y;
  const int bmi = (wid & 7) + 8 * (wid / (8 * NT));
  const int ny  = (wid >> 3) % NT;
  if (bmi >= MSTRIP) return;
  const int bm = bmi * 256;
  const int bn = ny * 128;

  auto stage = [&](int buf, int kk) {
    // A: 1024 16B-chunks over 512 threads (2 each)
#pragma unroll
    for (int it = 0; it < 2; ++it) {
      int s = it * 512 + tid;
      int row = s >> 2, kbl = s & 3;
      int kbg = kbl ^ ((row >> 1) & 3);        // pre-swizzled global source
      ld_lds16(A + (size_t)(bm + row) * LDA + kk + kbg * 8, &As[buf][s * 8]);
    }
    // B: 512 chunks, 1 each
    {
      int s = tid;
      int row = s >> 2, kbl = s & 3;
      int kbg = kbl ^ ((row >> 1) & 3);
      ld_lds16(B + (size_t)(bn + row) * LDB + kk + kbg * 8, &Bs[buf][s * 8]);
    }
  };

  f32x4v acc[4][4] = {};
  const int nt = K / 32;

  stage(0, 0);
  for (int t = 0; t < nt; ++t) {
    const int cur = t & 1;
    if (t + 1 < nt) {
      stage(cur ^ 1, (t + 1) * 32);                     // prefetch next tile (3 instr)
      asm volatile("s_waitcnt vmcnt(3)" ::: "memory");  // my stage(t) loads landed
    } else {
      asm volatile("s_waitcnt vmcnt(0)" ::: "memory");
    }
    __builtin_amdgcn_s_barrier();                       // raw: no vmcnt(0) drain
    asm volatile("" ::: "memory");

    bf16x8 af[4], bfr[4];
#pragma unroll
    for (int mi = 0; mi < 4; ++mi) {
      int r = wr * 64 + mi * 16 + l15;
      int kb = l4 ^ ((r >> 1) & 3);            // swizzled read
      af[mi] = *reinterpret_cast<const bf16x8*>(&As[cur][(r * 4 + kb) * 8]);
    }
#pragma unroll
    for (int ni = 0; ni < 4; ++ni) {
      int r = wc * 64 + ni * 16 + l15;
      int kb = l4 ^ ((r >> 1) & 3);
      bfr[ni] = *reinterpret_cast<const bf16x8*>(&Bs[cur][(r * 4 + kb) * 8]);
    }
#pragma unroll
    for (int mi = 0; mi < 4; ++mi)
#pragma unroll
      for (int ni = 0; ni < 4; ++ni)
        acc[mi][ni] = __builtin_amdgcn_mfma_f32_16x16x32_bf16(af[mi], bfr[ni], acc[mi][ni], 0, 0, 0);

    __builtin_amdgcn_s_barrier();                       // buf free for re-stage
    asm volatile("" ::: "memory");
  }

  const int slot = wid & (NSLOT - 1);
#pragma unroll
  for (int ni = 0; ni < 4; ++ni) {
    int col = bn + wc * 64 + ni * 16 + l15;
    float bv = bias[col];
    float s = 0.f, s2 = 0.f;
#pragma unroll
    for (int mi = 0; mi < 4; ++mi) {
      int row0 = bm + wr * 64 + mi * 16 + (l4 << 2);
#pragma unroll
      for (int r = 0; r < 4; ++r) {
        float v = acc[mi][ni][r] + bv;
        if (RELU) v = fmaxf(v, 0.f);
        if (OBF16) ((unsigned short*)C)[(size_t)(row0 + r) * NS + col] = f2bf(v);
        else       ((float*)C)[(size_t)(row0 + r) * NS + col] = v;
        if (STATS && (row0 + r) < NN) { s += v; s2 += v * v; }
      }
    }
    if (STATS) {
      s  += __shfl_xor(s, 16);  s  += __shfl_xor(s, 32);
      s2 += __shfl_xor(s2, 16); s2 += __shfl_xor(s2, 32);
      if (l4 == 0) {
        atomicAdd(&bnsum[slot * 384 + col], s);
        atomicAdd(&bnsum2[slot * 384 + col], s2);
      }
    }
  }
}

__global__ void bnfinal_kernel(const float* __restrict__ bnsum, const float* __restrict__ bnsum2,
                               const float* __restrict__ gamma, const float* __restrict__ beta,
                               int l, float* __restrict__ Aout, float* __restrict__ Bout) {
  int c = threadIdx.x;
  if (c >= 300) return;
  float s = 0.f, s2 = 0.f;
  for (int k = 0; k < NSLOT; ++k) { s += bnsum[k * 384 + c]; s2 += bnsum2[k * 384 + c]; }
  float mean = s * (1.f / NN);
  float var = s2 * (1.f / NN) - mean * mean;
  var = fmaxf(var, 0.f);
  float inv = rsqrtf(var + 1e-5f);
  float a = gamma[l * 300 + c] * inv;
  Aout[c] = a;
  Bout[c] = beta[l * 300 + c] - mean * a;
}

// ---------------- final BN apply (layer 4, no ReLU): d_out[N][300] = bf2f(z)*A + B
__global__ void bnapply_kernel(const unsigned short* __restrict__ z, const float* __restrict__ Ain,
                               const float* __restrict__ Bin, float* __restrict__ out) {
  int i = blockIdx.x * 256 + threadIdx.x;
  if (i >= NN * 75) return;
  int r = i / 75, q = i % 75;
  ushort4 zv = ((const ushort4*)z)[(size_t)r * 96 + q];
  float4 a = ((const float4*)Ain)[q];
  float4 b = ((const float4*)Bin)[q];
  float4 o;
  o.x = bf2f(zv.x) * a.x + b.x; o.y = bf2f(zv.y) * a.y + b.y;
  o.z = bf2f(zv.z) * a.z + b.z; o.w = bf2f(zv.w) * a.w + b.w;
  ((float4*)out)[i] = o;
}

// ---------------- workspace layout (bytes, all 256-aligned)
constexpr size_t OFF_Z    = 0;                               // z bf16 [MP][384]
constexpr size_t OFF_AB   = OFF_Z  + (size_t)MP * 384 * 2;   // abf16 [MP][320]
constexpr size_t OFF_Z1   = OFF_AB + (size_t)MP * 320 * 2;   // z1 bf16 [MP][640]
constexpr size_t OFF_WT1  = OFF_Z1 + (size_t)MP * 640 * 2;   // wt1 bf16 [640][320]
constexpr size_t OFF_WT2  = OFF_WT1 + 640 * 320 * 2;
constexpr size_t OFF_CMB  = OFF_WT2 + 384 * 640 * 2;
constexpr size_t OFF_SLF  = OFF_CMB + 14592;
constexpr size_t OFF_B1   = OFF_SLF + 1280;
constexpr size_t OFF_B2   = OFF_B1 + 2560;
constexpr size_t OFF_S1   = OFF_B2 + 1536;                   // bnsum  f32 [32][384]
constexpr size_t OFF_S2   = OFF_S1 + NSLOT * 384 * 4;        // bnsum2 f32 [32][384]
constexpr size_t OFF_BA   = OFF_S2 + NSLOT * 384 * 4;
constexpr size_t OFF_BB   = OFF_BA + 1536;
constexpr size_t OFF_DEG  = OFF_BB + 1536;              // int[NN]
constexpr size_t OFF_OFFS = OFF_DEG + 400384;           // int[NN]
constexpr size_t OFF_CUR  = OFF_OFFS + 400384;          // int[NN]
constexpr size_t OFF_BS   = OFF_CUR + 400384;           // int[NBLK]
constexpr size_t OFF_LIST = OFF_BS + 2048;              // int[NE]

extern "C" void kernel_launch(void* const* d_in, const int* in_sizes, int n_in,
                              void* d_out, int out_size, void* d_ws, size_t ws_size,
                              hipStream_t stream) {
  const int*   x     = (const int*)d_in[0];
  const int*   ei    = (const int*)d_in[1];
  const int*   ea    = (const int*)d_in[2];
  const float* xe1   = (const float*)d_in[3];
  const float* xe2   = (const float*)d_in[4];
  const float* ee1   = (const float*)d_in[5];
  const float* ee2   = (const float*)d_in[6];
  const float* W1    = (const float*)d_in[7];
  const float* b1    = (const float*)d_in[8];
  const float* W2    = (const float*)d_in[9];
  const float* b2    = (const float*)d_in[10];
  const float* eps   = (const float*)d_in[11];
  const float* gamma = (const float*)d_in[12];
  const float* beta  = (const float*)d_in[13];

  char* ws = (char*)d_ws;
  unsigned short* zf    = (unsigned short*)(ws + OFF_Z);
  unsigned short* abf   = (unsigned short*)(ws + OFF_AB);
  unsigned short* z1    = (unsigned short*)(ws + OFF_Z1);
  unsigned short* wt1   = (unsigned short*)(ws + OFF_WT1);
  unsigned short* wt2   = (unsigned short*)(ws + OFF_WT2);
  float*          combo = (float*)(ws + OFF_CMB);
  float*          selfv = (float*)(ws + OFF_SLF);
  float*          b1p   = (float*)(ws + OFF_B1);
  float*          b2p   = (float*)(ws + OFF_B2);
  float*          bns   = (float*)(ws + OFF_S1);
  float*          bns2  = (float*)(ws + OFF_S2);
  float*          bnA   = (float*)(ws + OFF_BA);
  float*          bnB   = (float*)(ws + OFF_BB);
  int*            deg   = (int*)(ws + OFF_DEG);
  int*            offs  = (int*)(ws + OFF_OFFS);
  int*            cur   = (int*)(ws + OFF_CUR);
  int*            bsum  = (int*)(ws + OFF_BS);
  int*            list  = (int*)(ws + OFF_LIST);

  const int g_ew   = (NN * 75 + 255) / 256;
  const int g_e    = (NE + 255) / 256;
  const int g_prep = (PREP_TOT + 255) / 256;
  const int GX     = 392;   // 49 groups of 8 row-strips (1 idle strip: 391)

  // one-time per launch: zero abf (pad rows/cols stay 0 across layers), deg
  hipMemsetAsync(abf, 0, (size_t)MP * 320 * 2, stream);
  hipMemsetAsync(deg, 0, NN * 4, stream);

  // CSR build (graph static across layers)
  deg_kernel<<<g_e, 256, 0, stream>>>(ei, deg);
  scan1_kernel<<<NBLK, SCAN_B, 0, stream>>>(deg, offs, bsum);
  scan2_kernel<<<1, 64, 0, stream>>>(bsum);
  scan3_kernel<<<NBLK, SCAN_B, 0, stream>>>(bsum, offs, cur);
  fill_kernel<<<g_e, 256, 0, stream>>>(ei, ea, cur, list);

  for (int l = 0; l < 5; ++l) {
    prep_kernel<<<g_prep, 256, 0, stream>>>(W1, W2, ee1, ee2, b1, b2, l,
                                            wt1, wt2, combo, selfv, b1p, b2p, bns, bns2);
    if (l == 0)
      gather_kernel<0><<<g_ew, 256, 0, stream>>>(zf, x, xe1, xe2, bnA, bnB,
                                                 offs, deg, list, combo, selfv, eps, l, abf);
    else
      gather_kernel<1><<<g_ew, 256, 0, stream>>>(zf, x, xe1, xe2, bnA, bnB,
                                                 offs, deg, list, combo, selfv, eps, l, abf);
    gemm_kernel<320, 320, 640, 5, true, true, false><<<dim3(GX, 5), 512, 0, stream>>>(
        abf, wt1, b1p, (void*)z1, 320, bns, bns2);
    gemm_kernel<640, 640, 384, 3, false, true, true><<<dim3(GX, 3), 512, 0, stream>>>(
        z1, wt2, b2p, (void*)zf, 640, bns, bns2);
    bnfinal_kernel<<<1, 384, 0, stream>>>(bns, bns2, gamma, beta, l, bnA, bnB);
  }
  bnapply_kernel<<<g_ew, 256, 0, stream>>>(zf, bnA, bnB, (float*)d_out);
}